// Round 6
// baseline (500.799 us; speedup 1.0000x reference)
//
#include <hip/hip_runtime.h>
#include <math.h>

#define NBb 16
#define NTt 50
#define NAa 5
#define NHh 128
#define NWw 128
#define NCc 20
#define NCH 26                       // 6 + NC channels
#define NCELL (NBb*NAa*NHh*NWw)      // 1,310,720 cells
#define NFLAT (NCELL*NCH)            // 34,078,720 floats
#define NQ4   (NFLAT/4)              // 8,519,680 float4s (exact)
#define NREC  (NBb*NTt)              // 800 records
#define SCALE_F 16.0f
#define IGNORE_THRES_F 0.5f
#define BAD_CONF_WEIGHT_F 1.25f
#define PI_F 3.14159265358979323846f
#define HSLOTS 8192                  // LDS hash slots (<=4800 unique cells)
#define GRID_MAIN 4096

typedef float __attribute__((ext_vector_type(4))) fvec4;

// ws layout (32-bit units):
//  [0]   acc_all (softplus over ALL cells; atomic partial sums)
//  [1]   ticket counter (uint, zeroed by k_prep)
//  [15]  pair counter (uint)
//  [16 .. 16+6*NREC)  records: tx,ty,tw,th,tr (float[NREC] each) + tlab (int[NREC])
//  [LIST_OFF ..)      (cell,val) pairs, 2 uints each, <= 4800 pairs
#define REC_OFF  16
#define LIST_OFF (REC_OFF + 6*NREC)

__device__ __forceinline__ float inv_tanh_f(float y) {
  if (y <= -1.0f) return -2.0f;
  if (y >= 1.0f)  return  2.0f;
  float ys = fminf(fmaxf(y, -1.0f + 1e-6f), 1.0f - 1e-6f);
  return 0.5f * logf((1.0f + ys) / (1.0f - ys));
}

// softplus(z) = max(z,0) + log1p(exp(-|z|))  == BCE(z, target=0)
__device__ __forceinline__ float softplus_f(float z) {
  return fmaxf(z, 0.0f) + log1pf(expf(-fabsf(z)));
}

// Single block: zero accumulators/tickets, then each of 800 threads processes
// one target record, appending (cell,val) pairs to a compact list.
// val = 1 (ignore) or 2+tid (mask).
__global__ void __launch_bounds__(1024) k_prep(const float* __restrict__ tgt,
                                               const int* __restrict__ tsz,
                                               const float* __restrict__ anch,
                                               float* __restrict__ ws) {
  unsigned* wsu = (unsigned*)ws;
  if (threadIdx.x < 32) wsu[threadIdx.x] = 0u;
  __syncthreads();
  int tid = threadIdx.x;
  if (tid >= NREC) return;
  int b = tid / NTt, t = tid % NTt;

  float aw[NAa], ah[NAa], ar[NAa], ahw[NAa], ap[NAa][8];
  for (int a = 0; a < NAa; ++a) {
    aw[a] = anch[a*3+0] / SCALE_F;
    ah[a] = anch[a*3+1] / SCALE_F;
    ar[a] = anch[a*3+2];
    float cr = cosf(ar[a]), sr = sinf(ar[a]);
    ap[a][0] = -cr*aw[a]; ap[a][1] =  sr*aw[a];
    ap[a][2] =  cr*aw[a]; ap[a][3] = -sr*aw[a];
    ap[a][4] = -sr*ah[a]; ap[a][5] = -cr*ah[a];
    ap[a][6] =  sr*ah[a]; ap[a][7] =  cr*ah[a];
    ahw[a] = (ah[a] + aw[a]) * 0.5f;
  }

  const float* row = tgt + (size_t)tid * (13 + NCc);
  float gx = row[0] / SCALE_F;
  float gy = row[1] / SCALE_F;
  float gr = row[2];
  float gh = row[3] / SCALE_F;
  float gw = row[4] / SCALE_F;
  bool valid = (t < tsz[b]) && (gw != 0.0f) && (gh != 0.0f);
  if (!valid) return;

  int gi = (int)gx; gi = min(max(gi, 0), NWw - 1);
  int gj = (int)gy; gj = min(max(gj, 0), NHh - 1);

  float cp[8];
  for (int k = 0; k < 8; ++k)
    cp[k] = row[5 + k] / SCALE_F - ((k & 1) ? gy : gx);

  float bestd = 1e30f; int best = 0; unsigned ignm = 0;
  for (int a = 0; a < NAa; ++a) {
    float dn = 0.0f;
    for (int p = 0; p < 8; p += 2) {
      float dx = cp[p]   - ap[a][p];
      float dy = cp[p+1] - ap[a][p+1];
      dn += sqrtf(dx*dx + dy*dy);
    }
    float nm = ((gh + gw) * 0.5f + ahw[a]) * 0.5f;
    float d = dn / nm; d = d * d;
    if (d < IGNORE_THRES_F) ignm |= (1u << a);
    if (d < bestd) { bestd = d; best = a; }
  }

  unsigned* list = wsu + LIST_OFF;
  int cellbase = ((b * NAa) * NHh + gj) * NWw + gi;
  for (int a = 0; a < NAa; ++a)
    if ((ignm >> a) & 1u) {
      unsigned slot = atomicAdd(&wsu[15], 1u);
      list[2*slot]   = (unsigned)(cellbase + a * NHh * NWw);
      list[2*slot+1] = 1u;
    }
  {
    unsigned slot = atomicAdd(&wsu[15], 1u);
    list[2*slot]   = (unsigned)(cellbase + best * NHh * NWw);
    list[2*slot+1] = 2u + (unsigned)tid;   // mask beats ignore; last t wins via max
  }

  float txv = inv_tanh_f(gx - ((float)gi + 0.5f));
  float tyv = inv_tanh_f(gy - ((float)gj + 0.5f));
  float rd = gr - ar[best];
  if (rd > PI_F) rd -= 2.0f * PI_F;
  else if (rd < -PI_F) rd += 2.0f * PI_F;
  float trv = inv_tanh_f(rd / (PI_F * 0.5f));
  float twv = logf(gw / aw[best] + 1e-16f);
  float thv = logf(gh / ah[best] + 1e-16f);
  int tlab = 0; float bm = row[13];
  for (int c = 1; c < NCc; ++c)
    if (row[13 + c] > bm) { bm = row[13 + c]; tlab = c; }

  float* rec = ws + REC_OFF;
  rec[0*NREC + tid] = txv;
  rec[1*NREC + tid] = tyv;
  rec[2*NREC + tid] = twv;
  rec[3*NREC + tid] = thv;
  rec[4*NREC + tid] = trv;
  ((int*)rec)[5*NREC + tid] = tlab;
}

// Fused stream + finalize. All blocks: coalesced float4 stream of the whole
// prediction tensor summing softplus(conf) (conf = .x when q%13==0, .z when
// q%13==6). Partial -> atomicAdd(ws[0]); fence; ticket. The block drawing the
// last ticket dedups the (cell,val) list in an LDS hash (packed key|val, one
// atomicMax word) and computes all masked losses + the final scalar.
__global__ void __launch_bounds__(256) k_main(const fvec4* __restrict__ pred4,
                                              const float* __restrict__ pred,
                                              float* __restrict__ ws,
                                              float* __restrict__ out) {
  unsigned* wsu = (unsigned*)ws;
  __shared__ unsigned hslot[HSLOTS];     // packed (cell<<11)|val ; 0 = empty
  __shared__ float red[4][10];
  __shared__ int amLastSh;

  float acc = 0.0f;
  int stride = gridDim.x * blockDim.x;
  for (int q = blockIdx.x * blockDim.x + threadIdx.x; q < NQ4; q += stride) {
    fvec4 v = pred4[q];
    int m13 = q % 13;
    if (m13 == 0)      acc += softplus_f(v.x);
    else if (m13 == 6) acc += softplus_f(v.z);
  }
  for (int off = 32; off; off >>= 1) acc += __shfl_down(acc, off, 64);
  int wid = threadIdx.x >> 6, lane = threadIdx.x & 63;
  if (lane == 0) red[wid][0] = acc;
  __syncthreads();
  if (threadIdx.x == 0) {
    float a = red[0][0] + red[1][0] + red[2][0] + red[3][0];
    atomicAdd(ws + 0, a);
    __threadfence();
    unsigned old = atomicAdd(&wsu[1], 1u);
    amLastSh = (old == gridDim.x - 1) ? 1 : 0;
  }
  __syncthreads();
  if (!amLastSh) return;

  // ---------- last block only: finalize ----------
  const unsigned* list = wsu + LIST_OFF;
  const float* rec = ws + REC_OFF;
  int npair = (int)wsu[15];

  for (int s = threadIdx.x; s < HSLOTS; s += 256) hslot[s] = 0u;
  __syncthreads();

  for (int i = threadIdx.x; i < npair; i += 256) {
    unsigned cell = list[2*i];
    unsigned packed = (cell << 11) | list[2*i+1];
    unsigned s = (cell * 2654435761u) >> 19;   // 13 bits
    for (;;) {
      unsigned cur = hslot[s];
      if (cur == 0u) {
        unsigned old = atomicCAS(&hslot[s], 0u, packed);
        if (old == 0u) break;
        cur = old;
      }
      if ((cur >> 11) == cell) { atomicMax(&hslot[s], packed); break; }
      s = (s + 1) & (HSLOTS - 1);
    }
  }
  __syncthreads();

  float sub = 0.0f, cnb = 0.0f, obj = 0.0f;
  float sx = 0.0f, sy = 0.0f, sw = 0.0f, sh = 0.0f, sr = 0.0f;
  float scls = 0.0f, cm = 0.0f;

  for (int s = threadIdx.x; s < HSLOTS; s += 256) {
    unsigned packed = hslot[s];
    if (packed == 0u) continue;
    unsigned cell = packed >> 11;
    unsigned st = packed & 2047u;
    const float* cp = pred + (size_t)cell * NCH;
    float z = cp[0];
    sub += softplus_f(z);
    cnb += 1.0f;
    if (st >= 2u) {
      int r = (int)(st - 2u);
      obj += softplus_f(z) - z;               // BCE(z, target=1)
      float dx = cp[1] - rec[0*NREC + r];
      float dy = cp[2] - rec[1*NREC + r];
      float dr = cp[3] - rec[4*NREC + r];
      float dh = cp[4] - rec[3*NREC + r];
      float dw = cp[5] - rec[2*NREC + r];
      sx += dx*dx; sy += dy*dy; sw += dw*dw; sh += dh*dh; sr += dr*dr;
      int tlab = ((const int*)rec)[5*NREC + r];
      float m = cp[6];
      for (int c = 1; c < NCc; ++c) m = fmaxf(m, cp[6 + c]);
      float s2 = 0.0f;
      for (int c = 0; c < NCc; ++c) s2 += expf(cp[6 + c] - m);
      scls += (m + logf(s2)) - cp[6 + tlab];
      cm += 1.0f;
    }
  }

  float vals[10] = {sub, cnb, obj, sx, sy, sw, sh, sr, scls, cm};
  for (int k = 0; k < 10; ++k) {
    float v = vals[k];
    for (int off = 32; off; off >>= 1) v += __shfl_down(v, off, 64);
    if (lane == 0) red[wid][k] = v;
  }
  __syncthreads();
  if (threadIdx.x == 0) {
    float tot[10];
    for (int k = 0; k < 10; ++k)
      tot[k] = red[0][k] + red[1][k] + red[2][k] + red[3][k];
    float acc_all = atomicAdd(ws + 0, 0.0f);   // coherent device-scope read
    float acc_bg = acc_all - tot[0];
    float cnt_bg = (float)NCELL - tot[1];
    float db = fmaxf(cnt_bg, 1.0f);
    float dm = fmaxf(tot[9], 1.0f);
    float loss_conf = BAD_CONF_WEIGHT_F * (acc_bg / db) + tot[2] / dm;
    out[0] = (tot[3] + tot[4] + tot[5] + tot[6] + tot[7] + tot[8]) / dm + loss_conf;
  }
}

extern "C" void kernel_launch(void* const* d_in, const int* in_sizes, int n_in,
                              void* d_out, int out_size, void* d_ws, size_t ws_size,
                              hipStream_t stream) {
  const float* pred = (const float*)d_in[0];   // (16,5,128,128,26)
  const float* tgt  = (const float*)d_in[1];   // (16,50,33)
  const int*   tsz  = (const int*)d_in[2];     // (16,)
  const float* anch = (const float*)d_in[3];   // (5,3)
  float* ws = (float*)d_ws;

  k_prep<<<1, 1024, 0, stream>>>(tgt, tsz, anch, ws);
  k_main<<<GRID_MAIN, 256, 0, stream>>>((const fvec4*)pred, pred, ws, (float*)d_out);
}

// Round 7
// 272.033 us; speedup vs baseline: 1.8410x; 1.8410x over previous
//
#include <hip/hip_runtime.h>
#include <math.h>

#define NBb 16
#define NTt 50
#define NAa 5
#define NHh 128
#define NWw 128
#define NCc 20
#define NCH 26                       // 6 + NC channels
#define NCELL (NBb*NAa*NHh*NWw)      // 1,310,720 cells
#define NFLAT (NCELL*NCH)            // 34,078,720 floats (136.3 MB)
#define NREC  (NBb*NTt)              // 800 records
#define SCALE_F 16.0f
#define IGNORE_THRES_F 0.5f
#define BAD_CONF_WEIGHT_F 1.25f
#define PI_F 3.14159265358979323846f
#define HSLOTS 8192                  // LDS hash slots (<=4800 unique cells)
#define HEMPTY 0xFFFFFFFFu

// Conf-line geometry: conf of cell i at byte 104*i. Per 13-line (832 B) group,
// exactly lines {0,1,3,4,6,8,9,11} contain one conf each. We stream only those
// lines: task j -> group j/32, w=j%32, line=tbl[w>>2], chunk-in-line=w&3.
// 4 consecutive lanes share one 64 B line -> 16 line-transactions per wave,
// same as a full stream, but only 8/13 of the bytes (84 MB vs 136 MB).
#define NGROUP (NFLAT*4/64/13)       // 163,840 line-groups (exact)
#define NTASK  (NGROUP*32)           // 5,242,880 16B-chunk tasks
#define TBLPACK 0xB9864310u          // {0,1,3,4,6,8,9,11} packed 4b each

typedef float __attribute__((ext_vector_type(4))) fvec4;

// ws layout (32-bit units):
//  [0]   acc_all (softplus over ALL cells, from k_sum)
//  [15]  pair counter (uint)
//  [16 .. 16+6*NREC)  records: tx,ty,tw,th,tr (float[NREC] each) + tlab (int[NREC])
//  [LIST_OFF ..)      (cell,val) pairs, 2 uints each, <= 4800 pairs
#define REC_OFF  16
#define LIST_OFF (REC_OFF + 6*NREC)

__device__ __forceinline__ float inv_tanh_f(float y) {
  if (y <= -1.0f) return -2.0f;
  if (y >= 1.0f)  return  2.0f;
  float ys = fminf(fmaxf(y, -1.0f + 1e-6f), 1.0f - 1e-6f);
  return 0.5f * logf((1.0f + ys) / (1.0f - ys));
}

// softplus(z) = max(z,0) + log1p(exp(-|z|))  == BCE(z, target=0)
__device__ __forceinline__ float softplus_f(float z) {
  return fmaxf(z, 0.0f) + log1pf(expf(-fabsf(z)));
}

// Single block: zero accumulators + counters, then each of 800 threads
// processes one target record, appending (cell,val) pairs to a compact list.
// val = 1 (ignore) or 2+tid (mask). No status grid, no fences.
__global__ void __launch_bounds__(1024) k_prep(const float* __restrict__ tgt,
                                               const int* __restrict__ tsz,
                                               const float* __restrict__ anch,
                                               float* __restrict__ ws) {
  unsigned* wsu = (unsigned*)ws;
  if (threadIdx.x < 16) wsu[threadIdx.x] = 0u;
  __syncthreads();
  int tid = threadIdx.x;
  if (tid >= NREC) return;
  int b = tid / NTt, t = tid % NTt;

  float aw[NAa], ah[NAa], ar[NAa], ahw[NAa], ap[NAa][8];
  for (int a = 0; a < NAa; ++a) {
    aw[a] = anch[a*3+0] / SCALE_F;
    ah[a] = anch[a*3+1] / SCALE_F;
    ar[a] = anch[a*3+2];
    float cr = cosf(ar[a]), sr = sinf(ar[a]);
    ap[a][0] = -cr*aw[a]; ap[a][1] =  sr*aw[a];
    ap[a][2] =  cr*aw[a]; ap[a][3] = -sr*aw[a];
    ap[a][4] = -sr*ah[a]; ap[a][5] = -cr*ah[a];
    ap[a][6] =  sr*ah[a]; ap[a][7] =  cr*ah[a];
    ahw[a] = (ah[a] + aw[a]) * 0.5f;
  }

  const float* row = tgt + (size_t)tid * (13 + NCc);
  float gx = row[0] / SCALE_F;
  float gy = row[1] / SCALE_F;
  float gr = row[2];
  float gh = row[3] / SCALE_F;
  float gw = row[4] / SCALE_F;
  bool valid = (t < tsz[b]) && (gw != 0.0f) && (gh != 0.0f);
  if (!valid) return;

  int gi = (int)gx; gi = min(max(gi, 0), NWw - 1);
  int gj = (int)gy; gj = min(max(gj, 0), NHh - 1);

  float cp[8];
  for (int k = 0; k < 8; ++k)
    cp[k] = row[5 + k] / SCALE_F - ((k & 1) ? gy : gx);

  float bestd = 1e30f; int best = 0; unsigned ignm = 0;
  for (int a = 0; a < NAa; ++a) {
    float dn = 0.0f;
    for (int p = 0; p < 8; p += 2) {
      float dx = cp[p]   - ap[a][p];
      float dy = cp[p+1] - ap[a][p+1];
      dn += sqrtf(dx*dx + dy*dy);
    }
    float nm = ((gh + gw) * 0.5f + ahw[a]) * 0.5f;
    float d = dn / nm; d = d * d;
    if (d < IGNORE_THRES_F) ignm |= (1u << a);
    if (d < bestd) { bestd = d; best = a; }
  }

  unsigned* list = wsu + LIST_OFF;
  int cellbase = ((b * NAa) * NHh + gj) * NWw + gi;
  for (int a = 0; a < NAa; ++a)
    if ((ignm >> a) & 1u) {
      unsigned slot = atomicAdd(&wsu[15], 1u);
      list[2*slot]   = (unsigned)(cellbase + a * NHh * NWw);
      list[2*slot+1] = 1u;
    }
  {
    unsigned slot = atomicAdd(&wsu[15], 1u);
    list[2*slot]   = (unsigned)(cellbase + best * NHh * NWw);
    list[2*slot+1] = 2u + (unsigned)tid;   // mask beats ignore; last t wins via max
  }

  float txv = inv_tanh_f(gx - ((float)gi + 0.5f));
  float tyv = inv_tanh_f(gy - ((float)gj + 0.5f));
  float rd = gr - ar[best];
  if (rd > PI_F) rd -= 2.0f * PI_F;
  else if (rd < -PI_F) rd += 2.0f * PI_F;
  float trv = inv_tanh_f(rd / (PI_F * 0.5f));
  float twv = logf(gw / aw[best] + 1e-16f);
  float thv = logf(gh / ah[best] + 1e-16f);
  int tlab = 0; float bm = row[13];
  for (int c = 1; c < NCc; ++c)
    if (row[13 + c] > bm) { bm = row[13 + c]; tlab = c; }

  float* rec = ws + REC_OFF;
  rec[0*NREC + tid] = txv;
  rec[1*NREC + tid] = tyv;
  rec[2*NREC + tid] = twv;
  rec[3*NREC + tid] = thv;
  rec[4*NREC + tid] = trv;
  ((int*)rec)[5*NREC + tid] = tlab;
}

// Streaming kernel (LDS-free, fence-free, minimal registers): sum
// softplus(conf) over all cells, reading ONLY the 64 B lines that contain a
// conf value. Chunk-in-group c (0..51): conf iff c%13==0 (.x) or c%13==6 (.z).
__global__ void __launch_bounds__(256) k_sum(const fvec4* __restrict__ pred4,
                                             float* __restrict__ ws) {
  float acc = 0.0f;
  int stride = gridDim.x * blockDim.x;
  for (int j = blockIdx.x * blockDim.x + threadIdx.x; j < NTASK; j += stride) {
    int grp = j >> 5;                 // 32 tasks per 13-line group
    int w   = j & 31;
    int line = (TBLPACK >> ((w >> 2) * 4)) & 15;   // {0,1,3,4,6,8,9,11}
    int c    = line * 4 + (w & 3);                 // chunk within group, 0..51
    int q    = grp * 52 + c;                       // global 16B-chunk index
    fvec4 v = pred4[q];
    int m13 = c % 13;                              // q%13 == c%13 (52 = 4*13)
    if (m13 == 0)      acc += softplus_f(v.x);
    else if (m13 == 6) acc += softplus_f(v.z);
  }
  for (int off = 32; off; off >>= 1) acc += __shfl_down(acc, off, 64);
  __shared__ float s0[4];
  int wid = threadIdx.x >> 6, lane = threadIdx.x & 63;
  if (lane == 0) s0[wid] = acc;
  __syncthreads();
  if (threadIdx.x == 0)
    atomicAdd(ws + 0, s0[0] + s0[1] + s0[2] + s0[3]);
}

// Single-block finalize: dedup/merge the pair list with an in-LDS
// open-addressed hash (atomicCAS on key, atomicMax on val == reference
// precedence), then compute corrections + masked losses and the final scalar.
__global__ void __launch_bounds__(1024) k_fixfin(const float* __restrict__ pred,
                                                 float* __restrict__ ws,
                                                 float* __restrict__ out) {
  unsigned* wsu = (unsigned*)ws;
  const unsigned* list = wsu + LIST_OFF;
  const float* rec = ws + REC_OFF;
  int npair = (int)wsu[15];

  __shared__ unsigned hkey[HSLOTS];
  __shared__ unsigned hval[HSLOTS];
  for (int s = threadIdx.x; s < HSLOTS; s += 1024) {
    hkey[s] = HEMPTY; hval[s] = 0u;
  }
  __syncthreads();

  for (int i = threadIdx.x; i < npair; i += 1024) {
    unsigned cell = list[2*i], v = list[2*i+1];
    unsigned s = (cell * 2654435761u) >> 19;   // top 13 bits
    for (;;) {
      unsigned k = atomicCAS(&hkey[s], HEMPTY, cell);
      if (k == HEMPTY || k == cell) { atomicMax(&hval[s], v); break; }
      s = (s + 1) & (HSLOTS - 1);
    }
  }
  __syncthreads();

  float sub = 0.0f, cnb = 0.0f, obj = 0.0f;
  float sx = 0.0f, sy = 0.0f, sw = 0.0f, sh = 0.0f, sr = 0.0f;
  float scls = 0.0f, cm = 0.0f;

  for (int s = threadIdx.x; s < HSLOTS; s += 1024) {
    unsigned cell = hkey[s];
    if (cell == HEMPTY) continue;
    unsigned st = hval[s];
    const float* cp = pred + (size_t)cell * NCH;
    float z = cp[0];
    sub += softplus_f(z);
    cnb += 1.0f;
    if (st >= 2u) {
      int r = (int)(st - 2u);
      obj += softplus_f(z) - z;               // BCE(z, target=1)
      float dx = cp[1] - rec[0*NREC + r];
      float dy = cp[2] - rec[1*NREC + r];
      float dr = cp[3] - rec[4*NREC + r];
      float dh = cp[4] - rec[3*NREC + r];
      float dw = cp[5] - rec[2*NREC + r];
      sx += dx*dx; sy += dy*dy; sw += dw*dw; sh += dh*dh; sr += dr*dr;
      int tlab = ((const int*)rec)[5*NREC + r];
      float m = cp[6];
      for (int c = 1; c < NCc; ++c) m = fmaxf(m, cp[6 + c]);
      float s2 = 0.0f;
      for (int c = 0; c < NCc; ++c) s2 += expf(cp[6 + c] - m);
      scls += (m + logf(s2)) - cp[6 + tlab];
      cm += 1.0f;
    }
  }

  // block reduction: 10 partials, shfl within wave then LDS across 16 waves
  float vals[10] = {sub, cnb, obj, sx, sy, sw, sh, sr, scls, cm};
  __shared__ float red[16][10];
  int wid = threadIdx.x >> 6, lane = threadIdx.x & 63;
  for (int k = 0; k < 10; ++k) {
    float v = vals[k];
    for (int off = 32; off; off >>= 1) v += __shfl_down(v, off, 64);
    if (lane == 0) red[wid][k] = v;
  }
  __syncthreads();
  if (threadIdx.x == 0) {
    float tot[10];
    for (int k = 0; k < 10; ++k) {
      float v = 0.0f;
      for (int w = 0; w < 16; ++w) v += red[w][k];
      tot[k] = v;
    }
    float acc_bg = ws[0] - tot[0];
    float cnt_bg = (float)NCELL - tot[1];
    float db = fmaxf(cnt_bg, 1.0f);
    float dm = fmaxf(tot[9], 1.0f);
    float loss_conf = BAD_CONF_WEIGHT_F * (acc_bg / db) + tot[2] / dm;
    out[0] = (tot[3] + tot[4] + tot[5] + tot[6] + tot[7] + tot[8]) / dm + loss_conf;
  }
}

extern "C" void kernel_launch(void* const* d_in, const int* in_sizes, int n_in,
                              void* d_out, int out_size, void* d_ws, size_t ws_size,
                              hipStream_t stream) {
  const float* pred = (const float*)d_in[0];   // (16,5,128,128,26)
  const float* tgt  = (const float*)d_in[1];   // (16,50,33)
  const int*   tsz  = (const int*)d_in[2];     // (16,)
  const float* anch = (const float*)d_in[3];   // (5,3)
  float* ws = (float*)d_ws;

  k_prep<<<1, 1024, 0, stream>>>(tgt, tsz, anch, ws);
  k_sum<<<4096, 256, 0, stream>>>((const fvec4*)pred, ws);
  k_fixfin<<<1, 1024, 0, stream>>>(pred, ws, (float*)d_out);
}

// Round 8
// 268.190 us; speedup vs baseline: 1.8673x; 1.0143x over previous
//
#include <hip/hip_runtime.h>
#include <math.h>

#define NBb 16
#define NTt 50
#define NAa 5
#define NHh 128
#define NWw 128
#define NCc 20
#define NCH 26                       // 6 + NC channels
#define NCELL (NBb*NAa*NHh*NWw)      // 1,310,720 cells
#define NFLAT (NCELL*NCH)            // 34,078,720 floats (136.3 MB)
#define NQ4   (NFLAT/4)              // 8,519,680 float4s (exact)
#define NREC  (NBb*NTt)              // 800 records
#define SCALE_F 16.0f
#define IGNORE_THRES_F 0.5f
#define BAD_CONF_WEIGHT_F 1.25f
#define PI_F 3.14159265358979323846f
#define HSLOTS 8192                  // LDS hash slots (<=4800 unique cells)
#define HEMPTY 0xFFFFFFFFu

typedef float __attribute__((ext_vector_type(4))) fvec4;

// ws layout (32-bit units):
//  [0]   acc_all (softplus over ALL cells, from k_sum)
//  [15]  pair counter (uint)
//  [16 .. 16+6*NREC)  records: tx,ty,tw,th,tr (float[NREC] each) + tlab (int[NREC])
//  [LIST_OFF ..)      (cell,val) pairs, 2 uints each, <= 4800 pairs
#define REC_OFF  16
#define LIST_OFF (REC_OFF + 6*NREC)

__device__ __forceinline__ float inv_tanh_f(float y) {
  if (y <= -1.0f) return -2.0f;
  if (y >= 1.0f)  return  2.0f;
  float ys = fminf(fmaxf(y, -1.0f + 1e-6f), 1.0f - 1e-6f);
  return 0.5f * logf((1.0f + ys) / (1.0f - ys));
}

// softplus(z) = max(z,0) + log1p(exp(-|z|))  == BCE(z, target=0)
__device__ __forceinline__ float softplus_f(float z) {
  return fmaxf(z, 0.0f) + log1pf(expf(-fabsf(z)));
}

// Single block: zero accumulators + counters, then each of 800 threads
// processes one target record, appending (cell,val) pairs to a compact list.
// val = 1 (ignore) or 2+tid (mask). No status grid, no fences.
__global__ void __launch_bounds__(1024) k_prep(const float* __restrict__ tgt,
                                               const int* __restrict__ tsz,
                                               const float* __restrict__ anch,
                                               float* __restrict__ ws) {
  unsigned* wsu = (unsigned*)ws;
  if (threadIdx.x < 16) wsu[threadIdx.x] = 0u;
  __syncthreads();
  int tid = threadIdx.x;
  if (tid >= NREC) return;
  int b = tid / NTt, t = tid % NTt;

  float aw[NAa], ah[NAa], ar[NAa], ahw[NAa], ap[NAa][8];
  for (int a = 0; a < NAa; ++a) {
    aw[a] = anch[a*3+0] / SCALE_F;
    ah[a] = anch[a*3+1] / SCALE_F;
    ar[a] = anch[a*3+2];
    float cr = cosf(ar[a]), sr = sinf(ar[a]);
    ap[a][0] = -cr*aw[a]; ap[a][1] =  sr*aw[a];
    ap[a][2] =  cr*aw[a]; ap[a][3] = -sr*aw[a];
    ap[a][4] = -sr*ah[a]; ap[a][5] = -cr*ah[a];
    ap[a][6] =  sr*ah[a]; ap[a][7] =  cr*ah[a];
    ahw[a] = (ah[a] + aw[a]) * 0.5f;
  }

  const float* row = tgt + (size_t)tid * (13 + NCc);
  float gx = row[0] / SCALE_F;
  float gy = row[1] / SCALE_F;
  float gr = row[2];
  float gh = row[3] / SCALE_F;
  float gw = row[4] / SCALE_F;
  bool valid = (t < tsz[b]) && (gw != 0.0f) && (gh != 0.0f);
  if (!valid) return;

  int gi = (int)gx; gi = min(max(gi, 0), NWw - 1);
  int gj = (int)gy; gj = min(max(gj, 0), NHh - 1);

  float cp[8];
  for (int k = 0; k < 8; ++k)
    cp[k] = row[5 + k] / SCALE_F - ((k & 1) ? gy : gx);

  float bestd = 1e30f; int best = 0; unsigned ignm = 0;
  for (int a = 0; a < NAa; ++a) {
    float dn = 0.0f;
    for (int p = 0; p < 8; p += 2) {
      float dx = cp[p]   - ap[a][p];
      float dy = cp[p+1] - ap[a][p+1];
      dn += sqrtf(dx*dx + dy*dy);
    }
    float nm = ((gh + gw) * 0.5f + ahw[a]) * 0.5f;
    float d = dn / nm; d = d * d;
    if (d < IGNORE_THRES_F) ignm |= (1u << a);
    if (d < bestd) { bestd = d; best = a; }
  }

  unsigned* list = wsu + LIST_OFF;
  int cellbase = ((b * NAa) * NHh + gj) * NWw + gi;
  for (int a = 0; a < NAa; ++a)
    if ((ignm >> a) & 1u) {
      unsigned slot = atomicAdd(&wsu[15], 1u);
      list[2*slot]   = (unsigned)(cellbase + a * NHh * NWw);
      list[2*slot+1] = 1u;
    }
  {
    unsigned slot = atomicAdd(&wsu[15], 1u);
    list[2*slot]   = (unsigned)(cellbase + best * NHh * NWw);
    list[2*slot+1] = 2u + (unsigned)tid;   // mask beats ignore; last t wins via max
  }

  float txv = inv_tanh_f(gx - ((float)gi + 0.5f));
  float tyv = inv_tanh_f(gy - ((float)gj + 0.5f));
  float rd = gr - ar[best];
  if (rd > PI_F) rd -= 2.0f * PI_F;
  else if (rd < -PI_F) rd += 2.0f * PI_F;
  float trv = inv_tanh_f(rd / (PI_F * 0.5f));
  float twv = logf(gw / aw[best] + 1e-16f);
  float thv = logf(gh / ah[best] + 1e-16f);
  int tlab = 0; float bm = row[13];
  for (int c = 1; c < NCc; ++c)
    if (row[13 + c] > bm) { bm = row[13 + c]; tlab = c; }

  float* rec = ws + REC_OFF;
  rec[0*NREC + tid] = txv;
  rec[1*NREC + tid] = tyv;
  rec[2*NREC + tid] = twv;
  rec[3*NREC + tid] = thv;
  rec[4*NREC + tid] = trv;
  ((int*)rec)[5*NREC + tid] = tlab;
}

// Streaming kernel (LDS-light, fence-free): sum softplus(conf) over ALL cells
// via a fully-sequential coalesced float4 stream of the whole prediction
// tensor. conf (channel 0) = .x when q%13==0, .z when q%13==6 (4q mod 26 even).
// Sequential full-stream beat both nontemporal (R5) and line-skipping (R7).
__global__ void __launch_bounds__(256) k_sum(const fvec4* __restrict__ pred4,
                                             float* __restrict__ ws) {
  float acc = 0.0f;
  int stride = gridDim.x * blockDim.x;
  for (int q = blockIdx.x * blockDim.x + threadIdx.x; q < NQ4; q += stride) {
    fvec4 v = pred4[q];
    int m13 = q % 13;
    if (m13 == 0)      acc += softplus_f(v.x);
    else if (m13 == 6) acc += softplus_f(v.z);
  }
  for (int off = 32; off; off >>= 1) acc += __shfl_down(acc, off, 64);
  __shared__ float s0[4];
  int wid = threadIdx.x >> 6, lane = threadIdx.x & 63;
  if (lane == 0) s0[wid] = acc;
  __syncthreads();
  if (threadIdx.x == 0)
    atomicAdd(ws + 0, s0[0] + s0[1] + s0[2] + s0[3]);
}

// Single-block finalize: dedup/merge the pair list with an in-LDS
// open-addressed hash (atomicCAS on key, atomicMax on val == reference
// precedence), then compute corrections + masked losses and the final scalar.
__global__ void __launch_bounds__(1024) k_fixfin(const float* __restrict__ pred,
                                                 float* __restrict__ ws,
                                                 float* __restrict__ out) {
  unsigned* wsu = (unsigned*)ws;
  const unsigned* list = wsu + LIST_OFF;
  const float* rec = ws + REC_OFF;
  int npair = (int)wsu[15];

  __shared__ unsigned hkey[HSLOTS];
  __shared__ unsigned hval[HSLOTS];
  for (int s = threadIdx.x; s < HSLOTS; s += 1024) {
    hkey[s] = HEMPTY; hval[s] = 0u;
  }
  __syncthreads();

  for (int i = threadIdx.x; i < npair; i += 1024) {
    unsigned cell = list[2*i], v = list[2*i+1];
    unsigned s = (cell * 2654435761u) >> 19;   // top 13 bits
    for (;;) {
      unsigned k = atomicCAS(&hkey[s], HEMPTY, cell);
      if (k == HEMPTY || k == cell) { atomicMax(&hval[s], v); break; }
      s = (s + 1) & (HSLOTS - 1);
    }
  }
  __syncthreads();

  float sub = 0.0f, cnb = 0.0f, obj = 0.0f;
  float sx = 0.0f, sy = 0.0f, sw = 0.0f, sh = 0.0f, sr = 0.0f;
  float scls = 0.0f, cm = 0.0f;

  for (int s = threadIdx.x; s < HSLOTS; s += 1024) {
    unsigned cell = hkey[s];
    if (cell == HEMPTY) continue;
    unsigned st = hval[s];
    const float* cp = pred + (size_t)cell * NCH;
    float z = cp[0];
    sub += softplus_f(z);
    cnb += 1.0f;
    if (st >= 2u) {
      int r = (int)(st - 2u);
      obj += softplus_f(z) - z;               // BCE(z, target=1)
      float dx = cp[1] - rec[0*NREC + r];
      float dy = cp[2] - rec[1*NREC + r];
      float dr = cp[3] - rec[4*NREC + r];
      float dh = cp[4] - rec[3*NREC + r];
      float dw = cp[5] - rec[2*NREC + r];
      sx += dx*dx; sy += dy*dy; sw += dw*dw; sh += dh*dh; sr += dr*dr;
      int tlab = ((const int*)rec)[5*NREC + r];
      float m = cp[6];
      for (int c = 1; c < NCc; ++c) m = fmaxf(m, cp[6 + c]);
      float s2 = 0.0f;
      for (int c = 0; c < NCc; ++c) s2 += expf(cp[6 + c] - m);
      scls += (m + logf(s2)) - cp[6 + tlab];
      cm += 1.0f;
    }
  }

  // block reduction: 10 partials, shfl within wave then LDS across 16 waves
  float vals[10] = {sub, cnb, obj, sx, sy, sw, sh, sr, scls, cm};
  __shared__ float red[16][10];
  int wid = threadIdx.x >> 6, lane = threadIdx.x & 63;
  for (int k = 0; k < 10; ++k) {
    float v = vals[k];
    for (int off = 32; off; off >>= 1) v += __shfl_down(v, off, 64);
    if (lane == 0) red[wid][k] = v;
  }
  __syncthreads();
  if (threadIdx.x == 0) {
    float tot[10];
    for (int k = 0; k < 10; ++k) {
      float v = 0.0f;
      for (int w = 0; w < 16; ++w) v += red[w][k];
      tot[k] = v;
    }
    float acc_bg = ws[0] - tot[0];
    float cnt_bg = (float)NCELL - tot[1];
    float db = fmaxf(cnt_bg, 1.0f);
    float dm = fmaxf(tot[9], 1.0f);
    float loss_conf = BAD_CONF_WEIGHT_F * (acc_bg / db) + tot[2] / dm;
    out[0] = (tot[3] + tot[4] + tot[5] + tot[6] + tot[7] + tot[8]) / dm + loss_conf;
  }
}

extern "C" void kernel_launch(void* const* d_in, const int* in_sizes, int n_in,
                              void* d_out, int out_size, void* d_ws, size_t ws_size,
                              hipStream_t stream) {
  const float* pred = (const float*)d_in[0];   // (16,5,128,128,26)
  const float* tgt  = (const float*)d_in[1];   // (16,50,33)
  const int*   tsz  = (const int*)d_in[2];     // (16,)
  const float* anch = (const float*)d_in[3];   // (5,3)
  float* ws = (float*)d_ws;

  k_prep<<<1, 1024, 0, stream>>>(tgt, tsz, anch, ws);
  k_sum<<<4096, 256, 0, stream>>>((const fvec4*)pred, ws);
  k_fixfin<<<1, 1024, 0, stream>>>(pred, ws, (float*)d_out);
}